// Round 17
// baseline (11140.686 us; speedup 1.0000x reference)
//
#include <hip/hip_runtime.h>
#include <hip/hip_bf16.h>
#include <cstdint>
#include <cstddef>

#define DEV __device__ __forceinline__

typedef _Float16 h2v __attribute__((ext_vector_type(2)));
typedef unsigned u4v __attribute__((ext_vector_type(4)));

DEV float sigmoidf_(float x) { return 1.0f / (1.0f + __expf(-x)); }
DEV float tanhf_(float x) {
    float e = __expf(2.0f * x);
    return 1.0f - 2.0f / (e + 1.0f);
}

// Load 16B of weights DIRECTLY INTO AGPRs (legal on gfx90a+/gfx950: memory
// ops accept AGPR data operands; R16 confirmed these assemble). Volatile asm
// -> cannot be rematerialized; lives in the AGPR file -> outside the VGPR
// allocator budget (60-92) that forced per-tick weight re-streaming R11-R15.
DEV u4v gload_a(const void* p) {
    u4v r;
    asm volatile("global_load_dwordx4 %0, %1, off\n\ts_waitcnt vmcnt(0)"
                 : "=a"(r) : "v"(p) : "memory");
    return r;
}

// R16 lesson: VOP3P (v_dot2_f32_f16) canNOT take an AGPR source on gfx950.
// So: explicit v_accvgpr_read_b32 into a temp VGPR, then the dot.
#define FDA(ACC, W, HW) { unsigned _t;                                        \
    asm("v_accvgpr_read_b32 %0, %2\n\tv_dot2_f32_f16 %1, %0, %3, %1"          \
        : "=&v"(_t), "+v"(ACC) : "a"(W), "v"(HW)); }

// LDS-only barrier: does NOT drain vmcnt; global prefetch/stores stay in flight.
#define LDS_BARRIER() asm volatile("s_waitcnt lgkmcnt(0)\n\ts_barrier" ::: "memory")

// ---------------------------------------------------------------------------
// Pack 10 matrices (256x64 each) to f16 pairs, split-K layout:
//   dst[m][half][qs][u][w]   (qs = q*4+s: gate q, slice s; w = word 0..3)
// m: 0-2 l1Whh, 3-5 l2Whh, 6-7 Wih12 (l1 layers 1,2), 8-9 l2Wih layers 1,2.
// ---------------------------------------------------------------------------
__global__ __launch_bounds__(256) void pack_w(
    const float* __restrict__ l1Whh, const float* __restrict__ l2Whh,
    const float* __restrict__ Wih12, const float* __restrict__ l2Wih,
    unsigned* __restrict__ wP)
{
    int idx = blockIdx.x * 256 + threadIdx.x;   // 10*8192 = 81920
    int m = idx >> 13;
    int rem = idx & 8191;
    int half = rem >> 12;
    int qs = (rem >> 8) & 15;
    int u = (rem >> 2) & 63;
    int w = rem & 3;
    int q = qs >> 2, s = qs & 3;
    int jp = 16 * half + 4 * s + w;

    const float* W;
    if (m < 3)      W = l1Whh + (size_t)m * 16384;
    else if (m < 6) W = l2Whh + (size_t)(m - 3) * 16384;
    else if (m < 8) W = Wih12 + (size_t)(m - 6) * 16384;
    else            W = l2Wih + (size_t)(m - 7) * 16384;   // layers 1,2

    const float* row = W + (size_t)(q * 64 + u) * 64;
    union { h2v h; unsigned u32; } c;
    c.h = (h2v){(_Float16)row[2 * jp], (_Float16)row[2 * jp + 1]};
    wP[idx] = c.u32;
}

// ---------------------------------------------------------------------------
// Input projection (layer 0 of each stack only): xg[b,t,u*4+q] unit-major.
// ---------------------------------------------------------------------------
__global__ __launch_bounds__(256) void proj_kernel(
    const float* __restrict__ x, const float* __restrict__ Wih,
    const float* __restrict__ bias, const float* __restrict__ gate,
    float* __restrict__ xg, int D, int T)
{
    __shared__ float xS[16 * 64];
    int tb = T / 16;
    int b  = blockIdx.x / tb;
    int t0 = (blockIdx.x % tb) * 16;
    int tid = threadIdx.x;

    int n = 16 * D;
    for (int e = tid; e < n; e += 256) {
        int t = e / D;
        int i = e - t * D;
        float v = x[((size_t)(b * T + t0 + t)) * D + i];
        if (gate) v += gate[b * T + t0 + t];
        xS[t * D + i] = v;
    }
    __syncthreads();

    int g = tid;
    float acc[16];
    float bg = bias[g];
#pragma unroll
    for (int t = 0; t < 16; t++) acc[t] = bg;

    const float* wr = Wih + (size_t)g * D;
    for (int i = 0; i < D; i++) {
        float w = wr[i];
#pragma unroll
        for (int t = 0; t < 16; t++) acc[t] += xS[t * D + i] * w;
    }

    float* og = xg + ((size_t)(b * T + t0)) * 256 + (g & 63) * 4 + (g >> 6);
#pragma unroll
    for (int t = 0; t < 16; t++) og[(size_t)t * 256] = acc[t];
}

// ---------------------------------------------------------------------------
// Pipelined 3-layer LSTM scan v17: ONE block per batch, TEN waves (the R12
// split: each wave 16 weight quads = 64 words -- the fewest per wave).
// Waves: 0,1 = L0 Whh halves; 2,3 = L1 Whh; 4,5 = L1 Wih; 6,7 = L2 Whh;
// 8,9 = L2 Wih. Weights AGPR-resident (gload_a, once); each dot2 pays one
// v_accvgpr_read (VOP3P can't read AGPRs -- R16). Per wave per tick:
// 64 reads + 64 dot2 = 128 VALU ops (~256 cyc); busiest SIMD <=3 waves.
// 80KB LDS pad keeps 1 wg/CU.
// ---------------------------------------------------------------------------
__global__ __launch_bounds__(640)
void scan3_kernel(
    const float* __restrict__ xg, const unsigned* __restrict__ whhP,
    const unsigned* __restrict__ wihP, const float* __restrict__ bvec,
    const float* __restrict__ h0, const float* __restrict__ c0,
    float* __restrict__ Hout, int T)
{
    __shared__ __align__(16) _Float16 hL[3][64];   // per-layer h (f16)
    __shared__ __align__(16) float4 exch[10][64];  // per-wave partials
    __shared__ float4 ldsPad[5120];                // 80KB: force 1 wg/CU
    int b = blockIdx.x;
    int tid = threadIdx.x;
    int wv = tid >> 6, u = tid & 63;
    if (T < 0) ((volatile float*)ldsPad)[u] = 0.f; // keep pad alive

    int layer = (wv < 2) ? 0 : (wv < 6 ? 1 : 2);
    int base  = (layer == 0) ? 0 : (layer == 1 ? 2 : 6);
    int idx   = wv - base;                 // 0..1 (L0) or 0..3 (L1,L2)
    bool isWih = (layer > 0) && (idx >= 2);
    int half  = isWih ? (idx - 2) : idx;   // k-half
    bool isRed = (idx == 0);
    int nsrc  = (layer == 0) ? 2 : 4;

    // 16 weight quads for this wave's matrix slice -> AGPRs
    const u4v* wp = isWih
        ? (const u4v*)wihP + (size_t)(layer - 1) * 2048 + (size_t)half * 1024 + u
        : (const u4v*)whhP + (size_t)layer * 2048 + (size_t)half * 1024 + u;
    u4v wI0 = gload_a(wp + 0 * 64),  wI1 = gload_a(wp + 1 * 64);
    u4v wI2 = gload_a(wp + 2 * 64),  wI3 = gload_a(wp + 3 * 64);
    u4v wF0 = gload_a(wp + 4 * 64),  wF1 = gload_a(wp + 5 * 64);
    u4v wF2 = gload_a(wp + 6 * 64),  wF3 = gload_a(wp + 7 * 64);
    u4v wG0 = gload_a(wp + 8 * 64),  wG1 = gload_a(wp + 9 * 64);
    u4v wG2 = gload_a(wp + 10 * 64), wG3 = gload_a(wp + 11 * 64);
    u4v wO0 = gload_a(wp + 12 * 64), wO1 = gload_a(wp + 13 * 64);
    u4v wO2 = gload_a(wp + 14 * 64), wO3 = gload_a(wp + 15 * 64);

    // reducer state: c, bias (L0 bias lives in xg)
    float c = 0.f;
    float4 bl = make_float4(0.f, 0.f, 0.f, 0.f);
    if (isRed) {
        c = c0[layer * 128 + b * 64 + u];
        hL[layer][u] = (_Float16)h0[layer * 128 + b * 64 + u];
        if (layer > 0) {
            const float* bb = bvec + layer * 256;
            bl = make_float4(bb[u], bb[64 + u], bb[128 + u], bb[192 + u]);
        }
    }
    __syncthreads();

    // h source for the dot: Whh waves read own layer; Wih waves read layer-1
    const u4v* hsrc = (const u4v*)(&hL[isWih ? layer - 1 : layer][0]) + half * 4;

    // x preacts: wave 0 only, consume-then-reload 4-deep (R10 fix)
    const float4* xp = (const float4*)(xg + (size_t)b * T * 256) + u;
    float4 xb[4];
    xb[0] = xb[1] = xb[2] = xb[3] = make_float4(0.f, 0.f, 0.f, 0.f);
    if (wv == 0) {
#pragma unroll
        for (int k = 0; k < 4; k++) xb[k] = xp[(size_t)k * 64];
    }

    float* hout = Hout + (size_t)b * T * 64 + u;

#define QSTEPA(S, WI, WF, WG, WO) { u4v hp = hsrc[S];                         \
    FDA(aI, WI.x, hp.x) FDA(aI, WI.y, hp.y) FDA(aI, WI.z, hp.z) FDA(aI, WI.w, hp.w) \
    FDA(aF, WF.x, hp.x) FDA(aF, WF.y, hp.y) FDA(aF, WF.z, hp.z) FDA(aF, WF.w, hp.w) \
    FDA(aG, WG.x, hp.x) FDA(aG, WG.y, hp.y) FDA(aG, WG.z, hp.z) FDA(aG, WG.w, hp.w) \
    FDA(aO, WO.x, hp.x) FDA(aO, WO.y, hp.y) FDA(aO, WO.z, hp.z) FDA(aO, WO.w, hp.w) }

    int Tt = T + 4;   // pipeline drain (T multiple of 4 -> Tt too)
    for (int t4 = 0; t4 < Tt; t4 += 4) {
#pragma unroll
        for (int k = 0; k < 4; k++) {
            int tick = t4 + k;

            float aI, aF, aG, aO;
            if (wv == 0) {
                float4 x = xb[k];
                aI = x.x; aF = x.y; aG = x.z; aO = x.w;
                int tp = tick + 4; if (tp > T - 1) tp = T - 1;
                xb[k] = xp[(size_t)tp * 64];   // wait lands 4 ticks later
            } else {
                aI = aF = aG = aO = 0.f;
            }

            QSTEPA(0, wI0, wF0, wG0, wO0)
            QSTEPA(1, wI1, wF1, wG1, wO1)
            QSTEPA(2, wI2, wF2, wG2, wO2)
            QSTEPA(3, wI3, wF3, wG3, wO3)

            exch[wv][u] = make_float4(aI, aF, aG, aO);
            LDS_BARRIER();   // partials visible

            if (isRed) {
                int tcur = tick - layer;
                if ((unsigned)tcur < (unsigned)T) {
                    float sI = aI + bl.x, sF = aF + bl.y;
                    float sG = aG + bl.z, sO = aO + bl.w;
                    for (int j = 1; j < nsrc; j++) {
                        float4 p = exch[base + j][u];
                        sI += p.x; sF += p.y; sG += p.z; sO += p.w;
                    }
                    c = sigmoidf_(sF) * c + sigmoidf_(sI) * tanhf_(sG);
                    float h = sigmoidf_(sO) * tanhf_(c);
                    hL[layer][u] = (_Float16)h;
                    if (layer == 2) hout[(size_t)tcur * 64] = h;
                }
            }
            LDS_BARRIER();   // h writes visible; WAR on exch protected
        }
    }
#undef QSTEPA
}

// ---------------------------------------------------------------------------
// Hc[b, {max,mean,std(ddof=1)}, t] over hidden dim (64). One wave per (b,t).
// ---------------------------------------------------------------------------
__global__ __launch_bounds__(256) void stats_kernel(
    const float* __restrict__ H, float* __restrict__ Hc, int T)
{
    int wid = threadIdx.x >> 6, lane = threadIdx.x & 63;
    int bt = blockIdx.x * 4 + wid;
    int b = bt / T, t = bt - b * T;

    float x = H[(size_t)bt * 64 + lane];
    float mx = x, sm = x;
#pragma unroll
    for (int m = 32; m >= 1; m >>= 1) {
        mx = fmaxf(mx, __shfl_xor(mx, m));
        sm += __shfl_xor(sm, m);
    }
    float mean = sm * (1.0f / 64.0f);
    float d = x - mean;
    float ss = d * d;
#pragma unroll
    for (int m = 32; m >= 1; m >>= 1) ss += __shfl_xor(ss, m);
    float sd = sqrtf(ss * (1.0f / 63.0f));

    if (lane == 0) {
        float* o = Hc + (size_t)b * 3 * T;
        o[0 * T + t] = mx;
        o[1 * T + t] = mean;
        o[2 * T + t] = sd;
    }
}

// ---------------------------------------------------------------------------
// Middle conv/BN chain, single workgroup (1024 threads).
// ---------------------------------------------------------------------------
template <int CIN, int COUT, int MODE>
DEV void conv_bn_stage(const float* __restrict__ in, const float* __restrict__ w,
                       const float* __restrict__ bias, float* __restrict__ out,
                       float* __restrict__ gate, int T, int tid,
                       float* rs, float* rq, float* stm, float* sti)
{
    float lsum[COUT], lss[COUT];
#pragma unroll
    for (int oc = 0; oc < COUT; oc++) { lsum[oc] = 0.f; lss[oc] = 0.f; }

    for (int k = 0; k < 8; k++) {
        int p = tid + k * 1024;
        int b = p / T;
        int t = p - b * T;
        float acc[COUT];
#pragma unroll
        for (int oc = 0; oc < COUT; oc++) acc[oc] = bias[oc];
#pragma unroll
        for (int ic = 0; ic < CIN; ic++) {
            const float* row = in + ((size_t)b * CIN + ic) * T;
            float xv[11];
#pragma unroll
            for (int kk = 0; kk < 11; kk++) {
                int tt = t + kk - 5;
                xv[kk] = (tt >= 0 && tt < T) ? row[tt] : 0.f;
            }
#pragma unroll
            for (int oc = 0; oc < COUT; oc++) {
                const float* wr = w + ((size_t)oc * CIN + ic) * 11;
#pragma unroll
                for (int kk = 0; kk < 11; kk++) acc[oc] += xv[kk] * wr[kk];
            }
        }
#pragma unroll
        for (int oc = 0; oc < COUT; oc++) {
            out[((size_t)b * COUT + oc) * T + t] = acc[oc];
            lsum[oc] += acc[oc];
            lss[oc] += acc[oc] * acc[oc];
        }
    }
    __syncthreads();

    int lane = tid & 63, wid = tid >> 6;
#pragma unroll
    for (int oc = 0; oc < COUT; oc++) {
        float s = lsum[oc], qq = lss[oc];
#pragma unroll
        for (int m = 32; m >= 1; m >>= 1) {
            s += __shfl_xor(s, m);
            qq += __shfl_xor(qq, m);
        }
        if (lane == 0) { rs[wid] = s; rq[wid] = qq; }
        __syncthreads();
        if (tid == 0) {
            float S = 0.f, Q = 0.f;
            for (int i = 0; i < 16; i++) { S += rs[i]; Q += rq[i]; }
            float m_ = S / (float)(2 * T);
            float v = Q / (float)(2 * T) - m_ * m_;
            stm[oc] = m_;
            sti[oc] = rsqrtf(v + 1e-5f);
        }
        __syncthreads();
    }

    for (int k = 0; k < 8; k++) {
        int p = tid + k * 1024;
        int b = p / T;
        int t = p - b * T;
#pragma unroll
        for (int oc = 0; oc < COUT; oc++) {
            size_t idx = ((size_t)b * COUT + oc) * T + t;
            float v = (out[idx] - stm[oc]) * sti[oc];
            if (MODE == 0) out[idx] = fmaxf(v, 0.f);
            else           gate[p] = sigmoidf_(v);
        }
    }
    __syncthreads();
}

__global__ __launch_bounds__(1024) void middle_kernel(
    const float* __restrict__ Hc,
    const float* __restrict__ w1, const float* __restrict__ b1,
    const float* __restrict__ w2, const float* __restrict__ b2,
    const float* __restrict__ w3, const float* __restrict__ b3,
    const float* __restrict__ w4, const float* __restrict__ b4,
    float* __restrict__ bufA, float* __restrict__ bufB,
    float* __restrict__ gate, int T)
{
    __shared__ float rs[16], rq[16], stm[8], sti[8];
    int tid = threadIdx.x;
    conv_bn_stage<3, 3, 0>(Hc,   w1, b1, bufA, nullptr, T, tid, rs, rq, stm, sti);
    conv_bn_stage<3, 5, 0>(bufA, w2, b2, bufB, nullptr, T, tid, rs, rq, stm, sti);
    conv_bn_stage<5, 5, 0>(bufB, w3, b3, bufA, nullptr, T, tid, rs, rq, stm, sti);
    conv_bn_stage<5, 1, 1>(bufA, w4, b4, bufB, gate,    T, tid, rs, rq, stm, sti);
}

// ---------------------------------------------------------------------------
// Head: y = sigmoid(fc2(fc1(out2))). One wave per (b,t).
// ---------------------------------------------------------------------------
__global__ __launch_bounds__(256) void final_kernel(
    const float* __restrict__ out2, const float* __restrict__ fc1w,
    const float* __restrict__ fc1b, const float* __restrict__ fc2w,
    const float* __restrict__ fc2b, float* __restrict__ out, int T)
{
    int wid = threadIdx.x >> 6, lane = threadIdx.x & 63;
    int bt = blockIdx.x * 4 + wid;

    const float* o2 = out2 + (size_t)bt * 64;
    float acc = fc1b[lane];
    const float* wr = fc1w + (size_t)lane * 64;
#pragma unroll
    for (int k = 0; k < 64; k++) acc += o2[k] * wr[k];

    float p = acc * fc2w[lane];
#pragma unroll
    for (int m = 32; m >= 1; m >>= 1) p += __shfl_xor(p, m);

    if (lane == 0) out[bt] = sigmoidf_(p + fc2b[0]);
}

// ---------------------------------------------------------------------------
extern "C" void kernel_launch(void* const* d_in, const int* in_sizes, int n_in,
                              void* d_out, int out_size, void* d_ws, size_t ws_size,
                              hipStream_t stream)
{
    const float* data  = (const float*)d_in[0];
    const float* h01   = (const float*)d_in[1];
    const float* c01   = (const float*)d_in[2];
    const float* h02   = (const float*)d_in[3];
    const float* c02   = (const float*)d_in[4];
    const float* Wih0  = (const float*)d_in[5];
    const float* Wih12 = (const float*)d_in[6];
    const float* l1Whh = (const float*)d_in[7];
    const float* l1b   = (const float*)d_in[8];
    const float* l2Wih = (const float*)d_in[9];
    const float* l2Whh = (const float*)d_in[10];
    const float* l2b   = (const float*)d_in[11];
    const float* cw1 = (const float*)d_in[12]; const float* cb1 = (const float*)d_in[13];
    const float* cw2 = (const float*)d_in[14]; const float* cb2 = (const float*)d_in[15];
    const float* cw3 = (const float*)d_in[16]; const float* cb3 = (const float*)d_in[17];
    const float* cw4 = (const float*)d_in[18]; const float* cb4 = (const float*)d_in[19];
    const float* fc1w = (const float*)d_in[20]; const float* fc1b = (const float*)d_in[21];
    const float* fc2w = (const float*)d_in[22]; const float* fc2b = (const float*)d_in[23];
    float* out = (float*)d_out;

    const int T = in_sizes[0] / (2 * 40);   // 4096
    const int B = 2;

    float* ws   = (float*)d_ws;
    float* xg   = ws;                                // B*T*256
    float* seqA = xg   + (size_t)B * T * 256;        // B*T*64
    float* seqB = seqA + (size_t)B * T * 64;         // B*T*64
    float* Hc   = seqB + (size_t)B * T * 64;         // B*3*T
    float* bufA = Hc   + (size_t)B * 3 * T;          // B*5*T
    float* bufB = bufA + (size_t)B * 5 * T;          // B*5*T
    float* gate = bufB + (size_t)B * 5 * T;          // B*T
    unsigned* wP = (unsigned*)(gate + (size_t)B * T); // 10*8192 u32

    dim3 pg(B * (T / 16)), pb(256);

    pack_w<<<320, 256, 0, stream>>>(l1Whh, l2Whh, Wih12, l2Wih, wP);

    // ---- LSTM1: proj layer0 + pipelined 3-layer scan ----
    proj_kernel<<<pg, pb, 0, stream>>>(data, Wih0, l1b, nullptr, xg, 40, T);
    scan3_kernel<<<2, 640, 0, stream>>>(xg, wP, wP + 6 * 8192, l1b, h01, c01, seqA, T);

    // ---- temporal-attention gate ----
    stats_kernel<<<(2 * T) / 4, 256, 0, stream>>>(seqA, Hc, T);
    middle_kernel<<<1, 1024, 0, stream>>>(Hc, cw1, cb1, cw2, cb2, cw3, cb3, cw4, cb4,
                                          bufA, bufB, gate, T);

    // ---- LSTM2: proj layer0 (gate folded) + pipelined 3-layer scan ----
    proj_kernel<<<pg, pb, 0, stream>>>(seqA, l2Wih, l2b, gate, xg, 64, T);
    scan3_kernel<<<2, 640, 0, stream>>>(xg, wP + 3 * 8192, wP + 8 * 8192, l2b, h02, c02, seqB, T);

    // ---- head ----
    final_kernel<<<(2 * T) / 4, 256, 0, stream>>>(seqB, fc1w, fc1b, fc2w, fc2b, out, T);
}

// Round 18
// 8746.640 us; speedup vs baseline: 1.2737x; 1.2737x over previous
//
#include <hip/hip_runtime.h>
#include <hip/hip_bf16.h>
#include <cstdint>
#include <cstddef>

#define DEV __device__ __forceinline__

typedef _Float16 h2v __attribute__((ext_vector_type(2)));
typedef unsigned u4v __attribute__((ext_vector_type(4)));

DEV float sigmoidf_(float x) { return 1.0f / (1.0f + __expf(-x)); }
DEV float tanhf_(float x) {
    float e = __expf(2.0f * x);
    return 1.0f - 2.0f / (e + 1.0f);
}
DEV h2v asH2(unsigned x) { union { unsigned u; h2v h; } c; c.u = x; return c.h; }

// LDS-only barrier: does NOT drain vmcnt; global prefetch/stores stay in flight.
#define LDS_BARRIER() asm volatile("s_waitcnt lgkmcnt(0)\n\ts_barrier" ::: "memory")

// ---------------------------------------------------------------------------
// Pack 10 matrices (256x64 each) to f16 pairs, split-K layout:
//   dst[m][half][qs][u][w]   (qs = q*4+s: gate q, slice s; w = word 0..3)
// m: 0-2 l1Whh, 3-5 l2Whh, 6-7 Wih12 (l1 layers 1,2), 8-9 l2Wih layers 1,2.
// ---------------------------------------------------------------------------
__global__ __launch_bounds__(256) void pack_w(
    const float* __restrict__ l1Whh, const float* __restrict__ l2Whh,
    const float* __restrict__ Wih12, const float* __restrict__ l2Wih,
    unsigned* __restrict__ wP)
{
    int idx = blockIdx.x * 256 + threadIdx.x;   // 10*8192 = 81920
    int m = idx >> 13;
    int rem = idx & 8191;
    int half = rem >> 12;
    int qs = (rem >> 8) & 15;
    int u = (rem >> 2) & 63;
    int w = rem & 3;
    int q = qs >> 2, s = qs & 3;
    int jp = 16 * half + 4 * s + w;

    const float* W;
    if (m < 3)      W = l1Whh + (size_t)m * 16384;
    else if (m < 6) W = l2Whh + (size_t)(m - 3) * 16384;
    else if (m < 8) W = Wih12 + (size_t)(m - 6) * 16384;
    else            W = l2Wih + (size_t)(m - 7) * 16384;   // layers 1,2

    const float* row = W + (size_t)(q * 64 + u) * 64;
    union { h2v h; unsigned u32; } c;
    c.h = (h2v){(_Float16)row[2 * jp], (_Float16)row[2 * jp + 1]};
    wP[idx] = c.u32;
}

// ---------------------------------------------------------------------------
// Input projection (layer 0 of each stack only): xg[b,t,u*4+q] unit-major.
// ---------------------------------------------------------------------------
__global__ __launch_bounds__(256) void proj_kernel(
    const float* __restrict__ x, const float* __restrict__ Wih,
    const float* __restrict__ bias, const float* __restrict__ gate,
    float* __restrict__ xg, int D, int T)
{
    __shared__ float xS[16 * 64];
    int tb = T / 16;
    int b  = blockIdx.x / tb;
    int t0 = (blockIdx.x % tb) * 16;
    int tid = threadIdx.x;

    int n = 16 * D;
    for (int e = tid; e < n; e += 256) {
        int t = e / D;
        int i = e - t * D;
        float v = x[((size_t)(b * T + t0 + t)) * D + i];
        if (gate) v += gate[b * T + t0 + t];
        xS[t * D + i] = v;
    }
    __syncthreads();

    int g = tid;
    float acc[16];
    float bg = bias[g];
#pragma unroll
    for (int t = 0; t < 16; t++) acc[t] = bg;

    const float* wr = Wih + (size_t)g * D;
    for (int i = 0; i < D; i++) {
        float w = wr[i];
#pragma unroll
        for (int t = 0; t < 16; t++) acc[t] += xS[t * D + i] * w;
    }

    float* og = xg + ((size_t)(b * T + t0)) * 256 + (g & 63) * 4 + (g >> 6);
#pragma unroll
    for (int t = 0; t < 16; t++) og[(size_t)t * 256] = acc[t];
}

// ---------------------------------------------------------------------------
// Per-wave matrix slice base (10-wave mapping, shared by copy + compute).
// ---------------------------------------------------------------------------
DEV const u4v* slice_base(const unsigned* whhP, const unsigned* wihP, int w) {
    int layer = (w < 2) ? 0 : (w < 6 ? 1 : 2);
    int base  = (layer == 0) ? 0 : (layer == 1 ? 2 : 6);
    int idx   = w - base;
    bool isWih = (layer > 0) && (idx >= 2);
    int half  = isWih ? (idx - 2) : idx;
    return isWih ? (const u4v*)wihP + (size_t)(layer - 1) * 2048 + (size_t)half * 1024
                 : (const u4v*)whhP + (size_t)layer * 2048 + (size_t)half * 1024;
}

// ---------------------------------------------------------------------------
// Pipelined 3-layer LSTM scan v18: ONE block per batch, TEN waves (R12 map).
// R11-R17 lesson: register residency for all 16 quads/wave is unobtainable
// (grant 60-68 at 10 waves; gfx950 AGPRs share the same unified budget).
// NEW: split the per-tick weight traffic across BOTH memory pipes --
//   gates I,F (8 quads): named-SSA registers; if the allocator remats them
//     they stream from L1 (~80KB/tick, ~1250cyc) -- half of R12's traffic;
//   gates G,O (8 quads): staged ONCE into 80KB of LDS, streamed per tick
//     via contiguous ds_read_b128 (1KB/instr full-bank sweeps, ~1000cyc)
//     on the LDS pipe, IN PARALLEL with the L1 stream.
// Tick ~ max(L1, LDS, VALU) ~ 1300-1600cyc vs R12's serial 2250.
// ---------------------------------------------------------------------------
__global__ __launch_bounds__(640)
void scan3_kernel(
    const float* __restrict__ xg, const unsigned* __restrict__ whhP,
    const unsigned* __restrict__ wihP, const float* __restrict__ bvec,
    const float* __restrict__ h0, const float* __restrict__ c0,
    float* __restrict__ Hout, int T)
{
    __shared__ __align__(16) _Float16 hL[3][64];   // per-layer h (f16)
    __shared__ __align__(16) float4 exch[10][64];  // per-wave partials
    __shared__ __align__(16) u4v wS[10 * 8 * 64];  // 80KB: streamed G,O quads
    int b = blockIdx.x;
    int tid = threadIdx.x;
    int wv = tid >> 6, u = tid & 63;

    int layer = (wv < 2) ? 0 : (wv < 6 ? 1 : 2);
    int base  = (layer == 0) ? 0 : (layer == 1 ? 2 : 6);
    int idx   = wv - base;                 // 0..1 (L0) or 0..3 (L1,L2)
    bool isWih = (layer > 0) && (idx >= 2);
    bool isRed = (idx == 0);
    int nsrc  = (layer == 0) ? 2 : 4;

    // stage gates G,O (quads 8..15) of every wave's slice into LDS, once
    for (int e = tid; e < 10 * 8 * 64; e += 640) {
        int w = e >> 9, j = (e >> 6) & 7, uu = e & 63;
        wS[e] = slice_base(whhP, wihP, w)[(8 + j) * 64 + uu];
    }

    // gates I,F (quads 0..7): named-SSA registers (pin; remat degrades to L1)
    const u4v* wp = slice_base(whhP, wihP, wv) + u;
    u4v rI0 = wp[0 * 64], rI1 = wp[1 * 64], rI2 = wp[2 * 64], rI3 = wp[3 * 64];
    u4v rF0 = wp[4 * 64], rF1 = wp[5 * 64], rF2 = wp[6 * 64], rF3 = wp[7 * 64];
    asm volatile("" : "+v"(rI0), "+v"(rI1), "+v"(rI2), "+v"(rI3),
                      "+v"(rF0), "+v"(rF1), "+v"(rF2), "+v"(rF3));

    // reducer state: c, bias (L0 bias lives in xg)
    float c = 0.f;
    float4 bl = make_float4(0.f, 0.f, 0.f, 0.f);
    if (isRed) {
        c = c0[layer * 128 + b * 64 + u];
        hL[layer][u] = (_Float16)h0[layer * 128 + b * 64 + u];
        if (layer > 0) {
            const float* bb = bvec + layer * 256;
            bl = make_float4(bb[u], bb[64 + u], bb[128 + u], bb[192 + u]);
        }
    }
    __syncthreads();

    // h source: Whh waves read own layer; Wih waves read layer-1.
    int half = isWih ? (idx - 2) : idx;
    const u4v* hsrc = (const u4v*)(&hL[isWih ? layer - 1 : layer][0]) + half * 4;
    const u4v* wsl  = wS + wv * 512 + u;   // streamed quad j at wsl[j*64]

    // x preacts: wave 0 only, consume-then-reload 2-deep
    const float4* xp = (const float4*)(xg + (size_t)b * T * 256) + u;
    float4 xb[2];
    xb[0] = xb[1] = make_float4(0.f, 0.f, 0.f, 0.f);
    if (wv == 0) {
        xb[0] = xp[0];
        xb[1] = xp[64];
    }

    float* hout = Hout + (size_t)b * T * 64 + u;

#define FD(HP, WV, ACC) ACC = __builtin_amdgcn_fdot2(asH2(HP), asH2(WV), ACC, false)
#define DOT4(HP, WQ, ACC) { FD(HP.x, WQ.x, ACC); FD(HP.y, WQ.y, ACC); \
                            FD(HP.z, WQ.z, ACC); FD(HP.w, WQ.w, ACC); }

    int Tt = T + 4;   // pipeline drain (multiple of 2)
    for (int t2 = 0; t2 < Tt; t2 += 2) {
#pragma unroll
        for (int k = 0; k < 2; k++) {
            int tick = t2 + k;

            float aI, aF, aG, aO;
            if (wv == 0) {
                float4 x = xb[k];
                aI = x.x; aF = x.y; aG = x.z; aO = x.w;
                int tp = tick + 2; if (tp > T - 1) tp = T - 1;
                xb[k] = xp[(size_t)tp * 64];   // wait lands 2 ticks later
            } else {
                aI = aF = aG = aO = 0.f;
            }

            // h quads once, reused by all four gates
            u4v hp0 = hsrc[0], hp1 = hsrc[1], hp2 = hsrc[2], hp3 = hsrc[3];

            // gates I,F from registers (or L1 remat -- half of R12 traffic)
            DOT4(hp0, rI0, aI) DOT4(hp1, rI1, aI) DOT4(hp2, rI2, aI) DOT4(hp3, rI3, aI)
            DOT4(hp0, rF0, aF) DOT4(hp1, rF1, aF) DOT4(hp2, rF2, aF) DOT4(hp3, rF3, aF)

            // gates G,O streamed from LDS (parallel pipe)
            {
                u4v g0 = wsl[0 * 64], g1 = wsl[1 * 64];
                DOT4(hp0, g0, aG)
                u4v g2 = wsl[2 * 64];
                DOT4(hp1, g1, aG)
                u4v g3 = wsl[3 * 64];
                DOT4(hp2, g2, aG) DOT4(hp3, g3, aG)
                u4v o0 = wsl[4 * 64], o1 = wsl[5 * 64];
                DOT4(hp0, o0, aO)
                u4v o2 = wsl[6 * 64];
                DOT4(hp1, o1, aO)
                u4v o3 = wsl[7 * 64];
                DOT4(hp2, o2, aO) DOT4(hp3, o3, aO)
            }

            exch[wv][u] = make_float4(aI, aF, aG, aO);
            LDS_BARRIER();   // partials visible

            if (isRed) {
                int tcur = tick - layer;
                if ((unsigned)tcur < (unsigned)T) {
                    float sI = aI + bl.x, sF = aF + bl.y;
                    float sG = aG + bl.z, sO = aO + bl.w;
                    for (int j = 1; j < nsrc; j++) {
                        float4 p = exch[base + j][u];
                        sI += p.x; sF += p.y; sG += p.z; sO += p.w;
                    }
                    c = sigmoidf_(sF) * c + sigmoidf_(sI) * tanhf_(sG);
                    float h = sigmoidf_(sO) * tanhf_(c);
                    hL[layer][u] = (_Float16)h;
                    if (layer == 2) hout[(size_t)tcur * 64] = h;
                }
            }
            LDS_BARRIER();   // h writes visible; WAR on exch protected
        }
    }
#undef FD
#undef DOT4
}

// ---------------------------------------------------------------------------
// Hc[b, {max,mean,std(ddof=1)}, t] over hidden dim (64). One wave per (b,t).
// ---------------------------------------------------------------------------
__global__ __launch_bounds__(256) void stats_kernel(
    const float* __restrict__ H, float* __restrict__ Hc, int T)
{
    int wid = threadIdx.x >> 6, lane = threadIdx.x & 63;
    int bt = blockIdx.x * 4 + wid;
    int b = bt / T, t = bt - b * T;

    float x = H[(size_t)bt * 64 + lane];
    float mx = x, sm = x;
#pragma unroll
    for (int m = 32; m >= 1; m >>= 1) {
        mx = fmaxf(mx, __shfl_xor(mx, m));
        sm += __shfl_xor(sm, m);
    }
    float mean = sm * (1.0f / 64.0f);
    float d = x - mean;
    float ss = d * d;
#pragma unroll
    for (int m = 32; m >= 1; m >>= 1) ss += __shfl_xor(ss, m);
    float sd = sqrtf(ss * (1.0f / 63.0f));

    if (lane == 0) {
        float* o = Hc + (size_t)b * 3 * T;
        o[0 * T + t] = mx;
        o[1 * T + t] = mean;
        o[2 * T + t] = sd;
    }
}

// ---------------------------------------------------------------------------
// Middle conv/BN chain, single workgroup (1024 threads).
// ---------------------------------------------------------------------------
template <int CIN, int COUT, int MODE>
DEV void conv_bn_stage(const float* __restrict__ in, const float* __restrict__ w,
                       const float* __restrict__ bias, float* __restrict__ out,
                       float* __restrict__ gate, int T, int tid,
                       float* rs, float* rq, float* stm, float* sti)
{
    float lsum[COUT], lss[COUT];
#pragma unroll
    for (int oc = 0; oc < COUT; oc++) { lsum[oc] = 0.f; lss[oc] = 0.f; }

    for (int k = 0; k < 8; k++) {
        int p = tid + k * 1024;
        int b = p / T;
        int t = p - b * T;
        float acc[COUT];
#pragma unroll
        for (int oc = 0; oc < COUT; oc++) acc[oc] = bias[oc];
#pragma unroll
        for (int ic = 0; ic < CIN; ic++) {
            const float* row = in + ((size_t)b * CIN + ic) * T;
            float xv[11];
#pragma unroll
            for (int kk = 0; kk < 11; kk++) {
                int tt = t + kk - 5;
                xv[kk] = (tt >= 0 && tt < T) ? row[tt] : 0.f;
            }
#pragma unroll
            for (int oc = 0; oc < COUT; oc++) {
                const float* wr = w + ((size_t)oc * CIN + ic) * 11;
#pragma unroll
                for (int kk = 0; kk < 11; kk++) acc[oc] += xv[kk] * wr[kk];
            }
        }
#pragma unroll
        for (int oc = 0; oc < COUT; oc++) {
            out[((size_t)b * COUT + oc) * T + t] = acc[oc];
            lsum[oc] += acc[oc];
            lss[oc] += acc[oc] * acc[oc];
        }
    }
    __syncthreads();

    int lane = tid & 63, wid = tid >> 6;
#pragma unroll
    for (int oc = 0; oc < COUT; oc++) {
        float s = lsum[oc], qq = lss[oc];
#pragma unroll
        for (int m = 32; m >= 1; m >>= 1) {
            s += __shfl_xor(s, m);
            qq += __shfl_xor(qq, m);
        }
        if (lane == 0) { rs[wid] = s; rq[wid] = qq; }
        __syncthreads();
        if (tid == 0) {
            float S = 0.f, Q = 0.f;
            for (int i = 0; i < 16; i++) { S += rs[i]; Q += rq[i]; }
            float m_ = S / (float)(2 * T);
            float v = Q / (float)(2 * T) - m_ * m_;
            stm[oc] = m_;
            sti[oc] = rsqrtf(v + 1e-5f);
        }
        __syncthreads();
    }

    for (int k = 0; k < 8; k++) {
        int p = tid + k * 1024;
        int b = p / T;
        int t = p - b * T;
#pragma unroll
        for (int oc = 0; oc < COUT; oc++) {
            size_t idx = ((size_t)b * COUT + oc) * T + t;
            float v = (out[idx] - stm[oc]) * sti[oc];
            if (MODE == 0) out[idx] = fmaxf(v, 0.f);
            else           gate[p] = sigmoidf_(v);
        }
    }
    __syncthreads();
}

__global__ __launch_bounds__(1024) void middle_kernel(
    const float* __restrict__ Hc,
    const float* __restrict__ w1, const float* __restrict__ b1,
    const float* __restrict__ w2, const float* __restrict__ b2,
    const float* __restrict__ w3, const float* __restrict__ b3,
    const float* __restrict__ w4, const float* __restrict__ b4,
    float* __restrict__ bufA, float* __restrict__ bufB,
    float* __restrict__ gate, int T)
{
    __shared__ float rs[16], rq[16], stm[8], sti[8];
    int tid = threadIdx.x;
    conv_bn_stage<3, 3, 0>(Hc,   w1, b1, bufA, nullptr, T, tid, rs, rq, stm, sti);
    conv_bn_stage<3, 5, 0>(bufA, w2, b2, bufB, nullptr, T, tid, rs, rq, stm, sti);
    conv_bn_stage<5, 5, 0>(bufB, w3, b3, bufA, nullptr, T, tid, rs, rq, stm, sti);
    conv_bn_stage<5, 1, 1>(bufA, w4, b4, bufB, gate,    T, tid, rs, rq, stm, sti);
}

// ---------------------------------------------------------------------------
// Head: y = sigmoid(fc2(fc1(out2))). One wave per (b,t).
// ---------------------------------------------------------------------------
__global__ __launch_bounds__(256) void final_kernel(
    const float* __restrict__ out2, const float* __restrict__ fc1w,
    const float* __restrict__ fc1b, const float* __restrict__ fc2w,
    const float* __restrict__ fc2b, float* __restrict__ out, int T)
{
    int wid = threadIdx.x >> 6, lane = threadIdx.x & 63;
    int bt = blockIdx.x * 4 + wid;

    const float* o2 = out2 + (size_t)bt * 64;
    float acc = fc1b[lane];
    const float* wr = fc1w + (size_t)lane * 64;
#pragma unroll
    for (int k = 0; k < 64; k++) acc += o2[k] * wr[k];

    float p = acc * fc2w[lane];
#pragma unroll
    for (int m = 32; m >= 1; m >>= 1) p += __shfl_xor(p, m);

    if (lane == 0) out[bt] = sigmoidf_(p + fc2b[0]);
}

// ---------------------------------------------------------------------------
extern "C" void kernel_launch(void* const* d_in, const int* in_sizes, int n_in,
                              void* d_out, int out_size, void* d_ws, size_t ws_size,
                              hipStream_t stream)
{
    const float* data  = (const float*)d_in[0];
    const float* h01   = (const float*)d_in[1];
    const float* c01   = (const float*)d_in[2];
    const float* h02   = (const float*)d_in[3];
    const float* c02   = (const float*)d_in[4];
    const float* Wih0  = (const float*)d_in[5];
    const float* Wih12 = (const float*)d_in[6];
    const float* l1Whh = (const float*)d_in[7];
    const float* l1b   = (const float*)d_in[8];
    const float* l2Wih = (const float*)d_in[9];
    const float* l2Whh = (const float*)d_in[10];
    const float* l2b   = (const float*)d_in[11];
    const float* cw1 = (const float*)d_in[12]; const float* cb1 = (const float*)d_in[13];
    const float* cw2 = (const float*)d_in[14]; const float* cb2 = (const float*)d_in[15];
    const float* cw3 = (const float*)d_in[16]; const float* cb3 = (const float*)d_in[17];
    const float* cw4 = (const float*)d_in[18]; const float* cb4 = (const float*)d_in[19];
    const float* fc1w = (const float*)d_in[20]; const float* fc1b = (const float*)d_in[21];
    const float* fc2w = (const float*)d_in[22]; const float* fc2b = (const float*)d_in[23];
    float* out = (float*)d_out;

    const int T = in_sizes[0] / (2 * 40);   // 4096
    const int B = 2;

    float* ws   = (float*)d_ws;
    float* xg   = ws;                                // B*T*256
    float* seqA = xg   + (size_t)B * T * 256;        // B*T*64
    float* seqB = seqA + (size_t)B * T * 64;         // B*T*64
    float* Hc   = seqB + (size_t)B * T * 64;         // B*3*T
    float* bufA = Hc   + (size_t)B * 3 * T;          // B*5*T
    float* bufB = bufA + (size_t)B * 5 * T;          // B*5*T
    float* gate = bufB + (size_t)B * 5 * T;          // B*T
    unsigned* wP = (unsigned*)(gate + (size_t)B * T); // 10*8192 u32

    dim3 pg(B * (T / 16)), pb(256);

    pack_w<<<320, 256, 0, stream>>>(l1Whh, l2Whh, Wih12, l2Wih, wP);

    // ---- LSTM1: proj layer0 + pipelined 3-layer scan ----
    proj_kernel<<<pg, pb, 0, stream>>>(data, Wih0, l1b, nullptr, xg, 40, T);
    scan3_kernel<<<2, 640, 0, stream>>>(xg, wP, wP + 6 * 8192, l1b, h01, c01, seqA, T);

    // ---- temporal-attention gate ----
    stats_kernel<<<(2 * T) / 4, 256, 0, stream>>>(seqA, Hc, T);
    middle_kernel<<<1, 1024, 0, stream>>>(Hc, cw1, cb1, cw2, cb2, cw3, cb3, cw4, cb4,
                                          bufA, bufB, gate, T);

    // ---- LSTM2: proj layer0 (gate folded) + pipelined 3-layer scan ----
    proj_kernel<<<pg, pb, 0, stream>>>(seqA, l2Wih, l2b, gate, xg, 64, T);
    scan3_kernel<<<2, 640, 0, stream>>>(xg, wP + 3 * 8192, wP + 8 * 8192, l2b, h02, c02, seqB, T);

    // ---- head ----
    final_kernel<<<(2 * T) / 4, 256, 0, stream>>>(seqB, fc1w, fc1b, fc2w, fc2b, out, T);
}